// Round 3
// baseline (77.747 us; speedup 1.0000x reference)
//
#include <hip/hip_runtime.h>
#include <hip/hip_bf16.h>
#include <stdint.h>

#define N 8192
#define D 256
#define PANEL 128                     // rows per block AND cols per block (symmetric tiling)
#define NPAN (N / PANEL)              // 64
#define TILE_N 16
#define NT (PANEL / TILE_N)           // 8
#define TILE_BYTES (TILE_N * D * 2)   // 8192 B
#define E_CONST 2.71828182845904523536f

typedef __attribute__((ext_vector_type(8))) short bf16x8;   // 8 bf16 (4 VGPRs)
typedef __attribute__((ext_vector_type(4))) float f32x4;

__device__ inline float bf2f(unsigned short u) {
  union { unsigned int i; float f; } c; c.i = ((unsigned)u) << 16; return c.f;
}
__device__ inline unsigned short f2bf(float x) {
  union { float f; unsigned int i; } c; c.f = x;
  unsigned int r = (c.i + 0x7fffu + ((c.i >> 16) & 1u)) >> 16;
  return (unsigned short)r;
}

typedef const __attribute__((address_space(1))) void gvoid_t;
typedef __attribute__((address_space(3))) void lvoid_t;
__device__ inline void gload_lds16(const void* g, void* l) {
  __builtin_amdgcn_global_load_lds((gvoid_t*)g, (lvoid_t*)l, 16, 0, 0);
}

// ---- kernel 1: row L2-normalize, fp32 -> bf16 ----
__global__ __launch_bounds__(256) void norm_kernel(const float* __restrict__ feat,
                                                   unsigned short* __restrict__ fbf) {
  int wave = threadIdx.x >> 6, lane = threadIdx.x & 63;
  int row = blockIdx.x * 4 + wave;
  const float4 v = *(const float4*)(feat + (size_t)row * D + lane * 4);
  float ss = v.x * v.x + v.y * v.y + v.z * v.z + v.w * v.w;
  for (int m = 1; m < 64; m <<= 1) ss += __shfl_xor(ss, m, 64);
  float rn = 1.0f / fmaxf(sqrtf(ss), 1e-12f);
  ushort4 o;
  o.x = f2bf(v.x * rn); o.y = f2bf(v.y * rn);
  o.z = f2bf(v.z * rn); o.w = f2bf(v.w * rn);
  *(ushort4*)(fbf + (size_t)row * D + lane * 4) = o;
}

// ---- kernel 2: positive-pair dot ----
__global__ __launch_bounds__(256) void pos_kernel(const unsigned short* __restrict__ fbf,
                                                  float* __restrict__ pos) {
  int wave = threadIdx.x >> 6, lane = threadIdx.x & 63;
  int row = blockIdx.x * 4 + wave;
  int partner = (row < N / 2) ? row + N / 2 : row - N / 2;
  const ushort4 a = *(const ushort4*)(fbf + (size_t)row * D + lane * 4);
  const ushort4 b = *(const ushort4*)(fbf + (size_t)partner * D + lane * 4);
  float d = bf2f(a.x) * bf2f(b.x) + bf2f(a.y) * bf2f(b.y) +
            bf2f(a.z) * bf2f(b.z) + bf2f(a.w) * bf2f(b.w);
  for (int m = 1; m < 64; m <<= 1) d += __shfl_xor(d, m, 64);
  if (lane == 0) pos[row] = d;
}

// ---- kernel 3: symmetric fused sim + partial sum(exp(sim)) ----
// Block (i,j), j>=i over 128x128 panels. Row-sums always; col-sums (symmetric
// mirror) when i!=j. Diagonal exp(sim_ii)~=e removed in final kernel.
__global__ __launch_bounds__(256, 4) void simlse_kernel(const unsigned short* __restrict__ fbf,
                                                        float* __restrict__ partial) {
  int pi = blockIdx.x >> 6, pj = blockIdx.x & 63;
  if (pj < pi) return;                 // triangular: 2080 live blocks

  __shared__ char lds[2 * TILE_BYTES];   // 16 KB
  const char* fb = (const char*)fbf;
  int tid = threadIdx.x;
  int wave = tid >> 6, lane = tid & 63;
  int l15 = lane & 15, lhi = lane >> 4;

  // A fragments: 2 m-tiles (32 rows/wave) x 8 k-steps, pinned in registers
  bf16x8 a[2][8];
  int rowbase = pi * PANEL + wave * 32;
#pragma unroll
  for (int mt = 0; mt < 2; ++mt) {
    size_t ar = (size_t)(rowbase + mt * 16 + l15) * (D * 2);
#pragma unroll
    for (int ks = 0; ks < 8; ++ks)
      a[mt][ks] = *(const bf16x8*)(fb + ar + lhi * 16 + ks * 64);
  }
#pragma unroll
  for (int mt = 0; mt < 2; ++mt)
#pragma unroll
    for (int ks = 0; ks < 8; ++ks)
      asm volatile("" : "+v"(a[mt][ks]));   // forbid rematerialization

  float s0[4] = {0, 0, 0, 0}, s1[4] = {0, 0, 0, 0};

  // staging geometry: 256 threads x 16B x 2 passes = one 8 KB tile; swizzled source
  int colbase = pj * PANEL;
  int o0 = tid * 16;            // 0..4095
  int o1 = o0 + 4096;
  int lrow0 = o0 >> 9, lrow1 = o1 >> 9;
  int goff0 = (o0 & 511) ^ ((lrow0 & 7) << 4);
  int goff1 = (o1 & 511) ^ ((lrow1 & 7) << 4);

  {  // prologue: stage tile 0 into buf 0
    gload_lds16(fb + (size_t)(colbase + lrow0) * 512 + goff0, lds + wave * 1024);
    gload_lds16(fb + (size_t)(colbase + lrow1) * 512 + goff1, lds + 4096 + wave * 1024);
  }

  for (int t = 0; t < NT; ++t) {
    int cur = t & 1;
    if (t + 1 < NT) {
      char* stg = lds + (cur ^ 1) * TILE_BYTES;
      size_t cb = (size_t)(colbase + (t + 1) * TILE_N);
      gload_lds16(fb + (cb + lrow0) * 512 + goff0, stg + wave * 1024);
      gload_lds16(fb + (cb + lrow1) * 512 + goff1, stg + 4096 + wave * 1024);
      asm volatile("s_waitcnt vmcnt(2)" ::: "memory");  // cur tile landed, next in flight
    } else {
      asm volatile("s_waitcnt vmcnt(0)" ::: "memory");
    }
    __builtin_amdgcn_s_barrier();
    __builtin_amdgcn_sched_barrier(0);

    f32x4 acc0 = {0, 0, 0, 0}, acc1 = {0, 0, 0, 0};
    const char* bb = lds + cur * TILE_BYTES;
    int rswz = (l15 & 7) << 4;
#pragma unroll
    for (int ks = 0; ks < 8; ++ks) {
      int kb = lhi * 16 + ks * 64;
      bf16x8 bfrag = *(const bf16x8*)(bb + l15 * 512 + (kb ^ rswz));
      acc0 = __builtin_amdgcn_mfma_f32_16x16x32_bf16(a[0][ks], bfrag, acc0, 0, 0, 0);
      acc1 = __builtin_amdgcn_mfma_f32_16x16x32_bf16(a[1][ks], bfrag, acc1, 0, 0, 0);
    }

    // exp + row-sums (always) + col-sums (mirror, off-diag blocks only)
    float e0[4], e1[4];
#pragma unroll
    for (int r = 0; r < 4; ++r) {
      e0[r] = __expf(acc0[r]);
      e1[r] = __expf(acc1[r]);
      s0[r] += e0[r];
      s1[r] += e1[r];
    }
    if (pi != pj) {
      float cs = (e0[0] + e0[1]) + (e0[2] + e0[3]) +
                 (e1[0] + e1[1]) + (e1[2] + e1[3]);   // this lane's 8 rows, col l15
      cs += __shfl_xor(cs, 16, 64);
      cs += __shfl_xor(cs, 32, 64);                   // sum over wave's 32 rows
      if (lane < 16) atomicAdd(&partial[colbase + t * TILE_N + lane], cs);
    }
    __builtin_amdgcn_sched_barrier(0);
    __builtin_amdgcn_s_barrier();
    __builtin_amdgcn_sched_barrier(0);
  }

  // row-wise reduce across the 16 lanes holding each row's columns
#pragma unroll
  for (int r = 0; r < 4; ++r) {
    for (int m = 1; m < 16; m <<= 1) {
      s0[r] += __shfl_xor(s0[r], m, 64);
      s1[r] += __shfl_xor(s1[r], m, 64);
    }
  }
  if (l15 == 0) {
#pragma unroll
    for (int r = 0; r < 4; ++r) {
      atomicAdd(&partial[rowbase + lhi * 4 + r], s0[r]);
      atomicAdd(&partial[rowbase + 16 + lhi * 4 + r], s1[r]);
    }
  }
}

// ---- kernel 4: combine partials -> scalar loss ----
__global__ __launch_bounds__(1024) void final_kernel(const float* __restrict__ partial,
                                                     const float* __restrict__ pos,
                                                     float* __restrict__ out) {
  int tid = threadIdx.x;
  float acc = 0.0f;
  for (int i = tid; i < N; i += 1024) {
    float s = partial[i] - E_CONST;          // remove diag exp(sim_ii) ~= e
    float lse = __logf(s);
    acc += lse - pos[i];
  }
  __shared__ float red[16];
  for (int m = 1; m < 64; m <<= 1) acc += __shfl_xor(acc, m, 64);
  int wave = tid >> 6, lane = tid & 63;
  if (lane == 0) red[wave] = acc;
  __syncthreads();
  if (tid == 0) {
    float t = 0.0f;
#pragma unroll
    for (int w = 0; w < 16; ++w) t += red[w];
    out[0] = t / (float)N;
  }
}

extern "C" void kernel_launch(void* const* d_in, const int* in_sizes, int n_in,
                              void* d_out, int out_size, void* d_ws, size_t ws_size,
                              hipStream_t stream) {
  const float* feat = (const float*)d_in[0];
  unsigned short* fbf = (unsigned short*)d_ws;                                   // 4 MB
  float* pos = (float*)((char*)d_ws + (size_t)N * D * 2);                        // 32 KB
  float* partial = (float*)((char*)d_ws + (size_t)N * D * 2 + (size_t)N * 4);    // 32 KB
  float* out = (float*)d_out;

  hipMemsetAsync(partial, 0, (size_t)N * 4, stream);
  norm_kernel<<<N / 4, 256, 0, stream>>>(feat, fbf);
  pos_kernel<<<N / 4, 256, 0, stream>>>(fbf, pos);
  simlse_kernel<<<NPAN * NPAN, 256, 0, stream>>>(fbf, partial);
  final_kernel<<<1, 1024, 0, stream>>>(partial, pos, out);
}

// Round 4
// 58.813 us; speedup vs baseline: 1.3219x; 1.3219x over previous
//
#include <hip/hip_runtime.h>
#include <hip/hip_bf16.h>
#include <stdint.h>

#define N 8192
#define D 256
#define ROWB 128                      // rows per simlse block (4 waves x 32)
#define COLG 16                       // column groups
#define COLS_PER_BLK (N / COLG)       // 512
#define TILE_N 16
#define NT (COLS_PER_BLK / TILE_N)    // 32
#define TILE_BYTES (TILE_N * D * 2)   // 8192 B
#define NBUF 4
#define E_CONST 2.71828182845904523536f

typedef __attribute__((ext_vector_type(8))) short bf16x8;   // 8 bf16 (4 VGPRs)
typedef __attribute__((ext_vector_type(4))) float f32x4;

__device__ inline float bf2f(unsigned short u) {
  union { unsigned int i; float f; } c; c.i = ((unsigned)u) << 16; return c.f;
}
__device__ inline unsigned short f2bf(float x) {
  union { float f; unsigned int i; } c; c.f = x;
  unsigned int r = (c.i + 0x7fffu + ((c.i >> 16) & 1u)) >> 16;
  return (unsigned short)r;
}

typedef const __attribute__((address_space(1))) void gvoid_t;
typedef __attribute__((address_space(3))) void lvoid_t;
__device__ inline void gload_lds16(const void* g, void* l) {
  __builtin_amdgcn_global_load_lds((gvoid_t*)g, (lvoid_t*)l, 16, 0, 0);
}

// ---- kernel 1: row L2-normalize, fp32 -> bf16 ----
__global__ __launch_bounds__(256) void norm_kernel(const float* __restrict__ feat,
                                                   unsigned short* __restrict__ fbf) {
  int wave = threadIdx.x >> 6, lane = threadIdx.x & 63;
  int row = blockIdx.x * 4 + wave;
  const float4 v = *(const float4*)(feat + (size_t)row * D + lane * 4);
  float ss = v.x * v.x + v.y * v.y + v.z * v.z + v.w * v.w;
  for (int m = 1; m < 64; m <<= 1) ss += __shfl_xor(ss, m, 64);
  float rn = 1.0f / fmaxf(sqrtf(ss), 1e-12f);
  ushort4 o;
  o.x = f2bf(v.x * rn); o.y = f2bf(v.y * rn);
  o.z = f2bf(v.z * rn); o.w = f2bf(v.w * rn);
  *(ushort4*)(fbf + (size_t)row * D + lane * 4) = o;
}

// ---- kernel 2: positive-pair dot ----
__global__ __launch_bounds__(256) void pos_kernel(const unsigned short* __restrict__ fbf,
                                                  float* __restrict__ pos) {
  int wave = threadIdx.x >> 6, lane = threadIdx.x & 63;
  int row = blockIdx.x * 4 + wave;
  int partner = (row < N / 2) ? row + N / 2 : row - N / 2;
  const ushort4 a = *(const ushort4*)(fbf + (size_t)row * D + lane * 4);
  const ushort4 b = *(const ushort4*)(fbf + (size_t)partner * D + lane * 4);
  float d = bf2f(a.x) * bf2f(b.x) + bf2f(a.y) * bf2f(b.y) +
            bf2f(a.z) * bf2f(b.z) + bf2f(a.w) * bf2f(b.w);
  for (int m = 1; m < 64; m <<= 1) d += __shfl_xor(d, m, 64);
  if (lane == 0) pos[row] = d;
}

// ---- kernel 3: fused sim tile + partial sum(exp(sim)); diag handled in final ----
// 4-deep LDS ring, one barrier per tile, counted vmcnt (never 0 until tail).
__global__ __launch_bounds__(256, 3) void simlse_kernel(const unsigned short* __restrict__ fbf,
                                                        float* __restrict__ partial) {
  __shared__ char lds[NBUF * TILE_BYTES];   // 32 KB
  const char* fb = (const char*)fbf;
  int tid = threadIdx.x;
  int wave = tid >> 6, lane = tid & 63;
  int l15 = lane & 15, lhi = lane >> 4;
  int rb = blockIdx.x >> 4;   // 0..63
  int cg = blockIdx.x & 15;   // 0..15

  // A fragments: 2 m-tiles (32 rows/wave) x 8 k-steps, pinned in registers
  bf16x8 a[2][8];
  int rowbase = rb * ROWB + wave * 32;
#pragma unroll
  for (int mt = 0; mt < 2; ++mt) {
    size_t ar = (size_t)(rowbase + mt * 16 + l15) * (D * 2);
#pragma unroll
    for (int ks = 0; ks < 8; ++ks)
      a[mt][ks] = *(const bf16x8*)(fb + ar + lhi * 16 + ks * 64);
  }
#pragma unroll
  for (int mt = 0; mt < 2; ++mt)
#pragma unroll
    for (int ks = 0; ks < 8; ++ks)
      asm volatile("" : "+v"(a[mt][ks]));   // forbid rematerialization / sinking

  float s0[4] = {0, 0, 0, 0}, s1[4] = {0, 0, 0, 0};

  // staging geometry: 256 threads x 16B x 2 passes = one 8 KB tile; swizzled source
  int colbase = cg * COLS_PER_BLK;
  int o0 = tid * 16;            // 0..4095
  int o1 = o0 + 4096;
  int lrow0 = o0 >> 9, lrow1 = o1 >> 9;
  int goff0 = (o0 & 511) ^ ((lrow0 & 7) << 4);
  int goff1 = (o1 & 511) ^ ((lrow1 & 7) << 4);

#define STAGE(tt)                                                              \
  {                                                                            \
    char* stg = lds + ((tt) & (NBUF - 1)) * TILE_BYTES;                        \
    size_t cb = (size_t)(colbase + (tt) * TILE_N);                             \
    gload_lds16(fb + (cb + lrow0) * 512 + goff0, stg + wave * 1024);           \
    gload_lds16(fb + (cb + lrow1) * 512 + goff1, stg + 4096 + wave * 1024);    \
  }

  STAGE(0);
  STAGE(1);

  for (int t = 0; t < NT; ++t) {
    if (t + 2 < NT) {
      STAGE(t + 2);                       // buf (t+2)&3: not read by any wave now
      asm volatile("s_waitcnt vmcnt(4)" ::: "memory");   // tile t landed; t+1,t+2 in flight
    } else if (t + 1 < NT) {
      asm volatile("s_waitcnt vmcnt(2)" ::: "memory");
    } else {
      asm volatile("s_waitcnt vmcnt(0)" ::: "memory");
    }
    __builtin_amdgcn_sched_barrier(0);
    __builtin_amdgcn_s_barrier();         // all waves' chunks of tile t visible
    __builtin_amdgcn_sched_barrier(0);

    f32x4 acc0 = {0, 0, 0, 0}, acc1 = {0, 0, 0, 0};
    const char* bb = lds + (t & (NBUF - 1)) * TILE_BYTES;
    int rswz = (l15 & 7) << 4;
#pragma unroll
    for (int ks = 0; ks < 8; ++ks) {
      int kb = lhi * 16 + ks * 64;
      bf16x8 bfrag = *(const bf16x8*)(bb + l15 * 512 + (kb ^ rswz));
      acc0 = __builtin_amdgcn_mfma_f32_16x16x32_bf16(a[0][ks], bfrag, acc0, 0, 0, 0);
      acc1 = __builtin_amdgcn_mfma_f32_16x16x32_bf16(a[1][ks], bfrag, acc1, 0, 0, 0);
    }

    // sum exp(sim) -- no diag mask; exp(sim_ii)=exp(1) subtracted in final kernel
#pragma unroll
    for (int r = 0; r < 4; ++r) {
      s0[r] += __expf(acc0[r]);
      s1[r] += __expf(acc1[r]);
    }
  }
#undef STAGE

  // row-wise reduce across the 16 lanes holding each row's columns
#pragma unroll
  for (int r = 0; r < 4; ++r) {
    for (int m = 1; m < 16; m <<= 1) {
      s0[r] += __shfl_xor(s0[r], m, 64);
      s1[r] += __shfl_xor(s1[r], m, 64);
    }
  }
  if (l15 == 0) {
#pragma unroll
    for (int r = 0; r < 4; ++r) {
      atomicAdd(&partial[rowbase + lhi * 4 + r], s0[r]);
      atomicAdd(&partial[rowbase + 16 + lhi * 4 + r], s1[r]);
    }
  }
}

// ---- kernel 4: combine partials -> scalar loss ----
__global__ __launch_bounds__(1024) void final_kernel(const float* __restrict__ partial,
                                                     const float* __restrict__ pos,
                                                     float* __restrict__ out) {
  int tid = threadIdx.x;
  float acc = 0.0f;
  for (int i = tid; i < N; i += 1024) {
    float s = partial[i] - E_CONST;          // remove diag exp(sim_ii) ~= e
    float lse = __logf(s);
    acc += lse - pos[i];
  }
  __shared__ float red[16];
  for (int m = 1; m < 64; m <<= 1) acc += __shfl_xor(acc, m, 64);
  int wave = tid >> 6, lane = tid & 63;
  if (lane == 0) red[wave] = acc;
  __syncthreads();
  if (tid == 0) {
    float t = 0.0f;
#pragma unroll
    for (int w = 0; w < 16; ++w) t += red[w];
    out[0] = t / (float)N;
  }
}

extern "C" void kernel_launch(void* const* d_in, const int* in_sizes, int n_in,
                              void* d_out, int out_size, void* d_ws, size_t ws_size,
                              hipStream_t stream) {
  const float* feat = (const float*)d_in[0];
  unsigned short* fbf = (unsigned short*)d_ws;                                   // 4 MB
  float* pos = (float*)((char*)d_ws + (size_t)N * D * 2);                        // 32 KB
  float* partial = (float*)((char*)d_ws + (size_t)N * D * 2 + (size_t)N * 4);    // 32 KB
  float* out = (float*)d_out;

  hipMemsetAsync(partial, 0, (size_t)N * 4, stream);
  norm_kernel<<<N / 4, 256, 0, stream>>>(feat, fbf);
  pos_kernel<<<N / 4, 256, 0, stream>>>(fbf, pos);
  simlse_kernel<<<(N / ROWB) * COLG, 256, 0, stream>>>(fbf, partial);
  final_kernel<<<1, 1024, 0, stream>>>(partial, pos, out);
}